// Round 4
// baseline (387.928 us; speedup 1.0000x reference)
//
#include <hip/hip_runtime.h>
#include <hip/hip_bf16.h>
#include <math.h>

// Problem constants (from reference setup_inputs)
#define NB 2
#define SEQ 2048
#define NH 16
#define DNOPE 128
#define DROT 64
#define DVDIM 128
#define DQK 192
#define BM 64
#define BN 32

typedef __bf16 bf16x8_t __attribute__((ext_vector_type(8)));
typedef float f32x4_t __attribute__((ext_vector_type(4)));

// log2(10000)/32 — inv_freq_i = 2^(-i*this); YaRN collapses (SCALING_FACTOR==1)
#define LOG2_BASE_OVER_HALFDIM 0.41524101186092028f
// 192^-0.5 * log2(e), folded into Q at bf16-convert time
#define KSL2 0.10412340175817158f
#define INV2PI 0.15915494309189535f

// ws layout
#define KBF_ELEMS   ((size_t)NB * NH * SEQ * DQK)          // 12,582,912
#define KPREP_BLOCKS 6144                                  // KBF_ELEMS/8/256
#define VPREP_BLOCKS 1024                                  // 32*16*2

// fast sin/cos of ang (radians, |ang|<~4096): reduce to revolutions in
// [-0.5,0.5], then v_sin/v_cos (input = revolutions). err ~2e-4 << bf16 ulp.
__device__ __forceinline__ void fast_sincos(float ang, float* sn, float* cs) {
  float rev = ang * INV2PI;
  float r = rev - rintf(rev);
  *sn = __builtin_amdgcn_sinf(r);
  *cs = __builtin_amdgcn_cosf(r);
}

// direct global->LDS DMA, 16B/lane; LDS dest is wave-uniform base + lane*16.
__device__ __forceinline__ void load_lds16(const __bf16* g, __bf16* l) {
  __builtin_amdgcn_global_load_lds(
      (const __attribute__((address_space(1))) unsigned int*)g,
      (__attribute__((address_space(3))) unsigned int*)l, 16, 0, 0);
}

// s_waitcnt vmcnt(0), expcnt/lgkm untouched (gfx9 encoding)
#define WAIT_VM0() __builtin_amdgcn_s_waitcnt(0x0F70)

// ---------------------------------------------------------------------------
// Fused prep: blocks [0,6144) build K bf16 [b][h][s][192] = concat(k_nope,
// rope(k_pe)); blocks [6144,7168) build V bf16 transposed [b][h][dv][s].
// ---------------------------------------------------------------------------
__global__ __launch_bounds__(256) void prep_kernel(
    const float* __restrict__ k_nope, const float* __restrict__ k_pe,
    const float* __restrict__ v, __bf16* __restrict__ Kbf,
    __bf16* __restrict__ Vtb) {
  __shared__ __bf16 T[64][130];
  const int bid = blockIdx.x;
  const int tid = threadIdx.x;
  if (bid < KPREP_BLOCKS) {
    int gid = bid * 256 + tid;                  // 8 elems each
    size_t o8 = (size_t)gid * 8;
    int d0 = (int)(o8 % DQK);                   // multiple of 8
    int rest = (int)(o8 / DQK);                 // (b*16+h)*2048 + s
    int s = rest & (SEQ - 1);
    int bh = rest >> 11;
    int h = bh & (NH - 1), b = bh >> 4;
    bf16x8_t o;
    if (d0 < DNOPE) {
      const float* p = k_nope + ((size_t)((b * SEQ + s) * NH + h)) * DNOPE + d0;
      float4 a = *(const float4*)p;
      float4 c = *(const float4*)(p + 4);
      o[0] = (__bf16)a.x; o[1] = (__bf16)a.y; o[2] = (__bf16)a.z; o[3] = (__bf16)a.w;
      o[4] = (__bf16)c.x; o[5] = (__bf16)c.y; o[6] = (__bf16)c.z; o[7] = (__bf16)c.w;
    } else {
      int dr0 = d0 - DNOPE;
      const float* p = k_pe + (size_t)(b * SEQ + s) * DROT;
#pragma unroll
      for (int j = 0; j < 8; ++j) {
        int dr = dr0 + j;
        int i = dr & 31;
        float invf = exp2f(-LOG2_BASE_OVER_HALFDIM * (float)i);
        float sn, cs;
        fast_sincos((float)s * invf, &sn, &cs);
        float x = p[dr];
        float oth = (dr < 32) ? -p[dr + 32] : p[dr - 32];
        o[j] = (__bf16)(x * cs + oth * sn);
      }
    }
    *(bf16x8_t*)&Kbf[o8] = o;
  } else {
    int vb = bid - KPREP_BLOCKS;
    const int s0 = (vb & 31) * 64, h = (vb >> 5) & (NH - 1), b = vb >> 9;
#pragma unroll
    for (int r = 0; r < 8; ++r) {
      int task = tid + r * 256;                 // 0..2047
      int srow = task >> 5, c4 = (task & 31) * 4;
      const float* p = v + ((size_t)((b * SEQ + s0 + srow) * NH + h)) * DVDIM + c4;
      float4 a = *(const float4*)p;
      T[srow][c4 + 0] = (__bf16)a.x; T[srow][c4 + 1] = (__bf16)a.y;
      T[srow][c4 + 2] = (__bf16)a.z; T[srow][c4 + 3] = (__bf16)a.w;
    }
    __syncthreads();
#pragma unroll
    for (int r = 0; r < 4; ++r) {
      int task = tid + r * 256;                 // 0..1023
      int dv = task >> 3, c8 = (task & 7) * 8;
      bf16x8_t o;
#pragma unroll
      for (int u = 0; u < 8; ++u) o[u] = T[c8 + u][dv];
      *(bf16x8_t*)&Vtb[((size_t)(b * NH + h) * DVDIM + dv) * SEQ + s0 + c8] = o;
    }
  }
}

// ---------------------------------------------------------------------------
// Flash attention fwd. Grid (32, NH, NB): one BM=64 q-tile per WG, biggest
// first. K-loop over BN=32 k-tiles, count = 2qt+2 (always even) -> manual
// 2x unroll over statically-distinct LDS double buffers (KlA/KlB, VlA/VlB)
// staged by global_load_lds DMA. One barrier per tile; s_waitcnt vmcnt(0)
// BEFORE each barrier drains DMAs issued a full compute-phase earlier and
// (with the barrier) guarantees cross-wave completion. Prefetch for tile
// t+1 is issued right after the barrier -> overlaps all of tile t's compute.
// l is accumulated by MFMA against a static ones-column tile Vx.
// ---------------------------------------------------------------------------
__global__ __launch_bounds__(256, 2) void mla_fwd_kernel(
    const float* __restrict__ q_nope, const float* __restrict__ q_pe,
    const __bf16* __restrict__ Kbf, const __bf16* __restrict__ Vtb,
    float* __restrict__ out_o, float* __restrict__ out_lse) {
  __shared__ __bf16 KlA[BN * DQK];      // 12288 B
  __shared__ __bf16 KlB[BN * DQK];      // 12288 B
  __shared__ __bf16 VlA[DVDIM * BN];    //  8192 B
  __shared__ __bf16 VlB[DVDIM * BN];    //  8192 B
  __shared__ __bf16 Pl[4][16 * BN];     //  4096 B
  __shared__ __bf16 Vx[16 * BN];        //  1024 B   -> 45 KB total

  const int qt = 31 - (int)blockIdx.x;  // big tiles first
  const int h = blockIdx.y, b = blockIdx.z;
  const int qb = qt * BM;
  const int tid = threadIdx.x;
  const int w = tid >> 6, lane = tid & 63;
  const int col = lane & 15, quad = lane >> 4;
  const int swz = col & 7;
  const int e0 = quad ^ swz, e1 = (quad + 4) ^ swz;  // K-row swizzled blocks

  // ones-column tile: row 0 = ones over 32 keys, rows 1..15 = 0
  for (int i = tid; i < 16 * BN; i += 256)
    Vx[i] = (i < BN) ? (__bf16)1.0f : (__bf16)0.0f;

  const __bf16* Kslab = Kbf + (size_t)(b * NH + h) * SEQ * DQK;
  const __bf16* Vslab = Vtb + (size_t)(b * NH + h) * DVDIM * SEQ;

  // staging source offsets. K keeps the XOR swizzle (row=24 16B-blocks,
  // stride 384B = 0 mod 128B, so the XOR makes read start-classes uniform);
  // V rows are 64B (class = 16*(dv&1)+4j, already uniform) -> identity.
  int kofs[3];
#pragma unroll
  for (int r = 0; r < 3; ++r) {
    int L = r * 256 + tid;                 // 16B block 0..767
    int n = L / 24, jj = L - n * 24;
    int jsrc = (jj & ~7) | ((jj & 7) ^ (n & 7));
    kofs[r] = n * DQK + jsrc * 8;
  }
  int vofs[2];
#pragma unroll
  for (int r = 0; r < 2; ++r) {
    int L = r * 256 + tid;                 // 0..511
    vofs[r] = (L >> 2) * SEQ + (L & 3) * 8;
  }

  __syncthreads();                         // Vx visible (before any DMA)
  const bf16x8_t vxf = *(const bf16x8_t*)&Vx[col * BN + quad * 8];

  auto stage = [&](int tile, __bf16* Kd, __bf16* Vd) {
    const __bf16* Ks = Kslab + (size_t)tile * BN * DQK;
    const __bf16* Vs = Vslab + tile * BN;
#pragma unroll
    for (int r = 0; r < 3; ++r) load_lds16(Ks + kofs[r], &Kd[(r * 256 + tid) * 8]);
#pragma unroll
    for (int r = 0; r < 2; ++r) load_lds16(Vs + vofs[r], &Vd[(r * 256 + tid) * 8]);
  };

  stage(0, KlA, VlA);                      // prologue DMA overlaps Q setup

  // ---- Q fragments (A-layout: A[m=lane&15][k=quad*8+j]); scale folded in.
  const int mrow = qb + w * 16 + col;
  const float* qn = q_nope + (size_t)((b * SEQ + mrow) * NH + h) * DNOPE;
  const float* qp = q_pe   + (size_t)((b * SEQ + mrow) * NH + h) * DROT;
  bf16x8_t qfrag[6];
#pragma unroll
  for (int c = 0; c < 4; ++c) {
    const float* p = qn + c * 32 + quad * 8;
    float4 a = *(const float4*)p;
    float4 bq = *(const float4*)(p + 4);
    bf16x8_t f;
    f[0]=(__bf16)(a.x*KSL2);  f[1]=(__bf16)(a.y*KSL2);
    f[2]=(__bf16)(a.z*KSL2);  f[3]=(__bf16)(a.w*KSL2);
    f[4]=(__bf16)(bq.x*KSL2); f[5]=(__bf16)(bq.y*KSL2);
    f[6]=(__bf16)(bq.z*KSL2); f[7]=(__bf16)(bq.w*KSL2);
    qfrag[c] = f;
  }
  {
    const float* plo = qp + quad * 8;
    const float* phi = qp + 32 + quad * 8;
    float4 lo0 = *(const float4*)plo;
    float4 lo1 = *(const float4*)(plo + 4);
    float4 hi0 = *(const float4*)phi;
    float4 hi1 = *(const float4*)(phi + 4);
    float xl[8] = {lo0.x,lo0.y,lo0.z,lo0.w,lo1.x,lo1.y,lo1.z,lo1.w};
    float xh[8] = {hi0.x,hi0.y,hi0.z,hi0.w,hi1.x,hi1.y,hi1.z,hi1.w};
    bf16x8_t f4v, f5v;
#pragma unroll
    for (int j = 0; j < 8; ++j) {
      int i = quad * 8 + j;
      float invf = exp2f(-LOG2_BASE_OVER_HALFDIM * (float)i);
      float sn, cs;
      fast_sincos((float)mrow * invf, &sn, &cs);
      f4v[j] = (__bf16)((xl[j] * cs - xh[j] * sn) * KSL2);
      f5v[j] = (__bf16)((xh[j] * cs + xl[j] * sn) * KSL2);
    }
    qfrag[4] = f4v; qfrag[5] = f5v;
  }

  f32x4_t oacc[8];
#pragma unroll
  for (int i = 0; i < 8; ++i) oacc[i] = (f32x4_t){0.f, 0.f, 0.f, 0.f};
  f32x4_t lacc = (f32x4_t){0.f, 0.f, 0.f, 0.f};
  float m_run[4] = {-INFINITY, -INFINITY, -INFINITY, -INFINITY};

  auto compute = [&](const __bf16* Kt, const __bf16* Vt, int kb) {
    // S = Q K^T : 2 n-tiles, 6 K-chunks (pre-scaled, log2 domain)
    f32x4_t sacc[2];
#pragma unroll
    for (int t = 0; t < 2; ++t) sacc[t] = (f32x4_t){0.f, 0.f, 0.f, 0.f};
#pragma unroll
    for (int t = 0; t < 2; ++t) {
      const __bf16* kr = &Kt[(t * 16 + col) * DQK];
      sacc[t] = __builtin_amdgcn_mfma_f32_16x16x32_bf16(qfrag[0], *(const bf16x8_t*)&kr[e0 * 8], sacc[t], 0, 0, 0);
      sacc[t] = __builtin_amdgcn_mfma_f32_16x16x32_bf16(qfrag[1], *(const bf16x8_t*)&kr[e1 * 8], sacc[t], 0, 0, 0);
      sacc[t] = __builtin_amdgcn_mfma_f32_16x16x32_bf16(qfrag[2], *(const bf16x8_t*)&kr[64 + e0 * 8], sacc[t], 0, 0, 0);
      sacc[t] = __builtin_amdgcn_mfma_f32_16x16x32_bf16(qfrag[3], *(const bf16x8_t*)&kr[64 + e1 * 8], sacc[t], 0, 0, 0);
      sacc[t] = __builtin_amdgcn_mfma_f32_16x16x32_bf16(qfrag[4], *(const bf16x8_t*)&kr[128 + e0 * 8], sacc[t], 0, 0, 0);
      sacc[t] = __builtin_amdgcn_mfma_f32_16x16x32_bf16(qfrag[5], *(const bf16x8_t*)&kr[128 + e1 * 8], sacc[t], 0, 0, 0);
    }

    // online softmax (log2 domain); mask only when tile crosses the diagonal
    const bool mk = (kb + BN - 1 > qb + w * 16);   // wave-uniform
    float pv0[4], pv1[4], alpha[4];
#pragma unroll
    for (int r = 0; r < 4; ++r) {
      float s0 = sacc[0][r], s1 = sacc[1][r];
      if (mk) {
        int mm = qb + w * 16 + quad * 4 + r;
        if (kb + col > mm)      s0 = -INFINITY;
        if (kb + 16 + col > mm) s1 = -INFINITY;
      }
      float mx = fmaxf(s0, s1);
      mx = fmaxf(mx, __shfl_xor(mx, 1, 64));
      mx = fmaxf(mx, __shfl_xor(mx, 2, 64));
      mx = fmaxf(mx, __shfl_xor(mx, 4, 64));
      mx = fmaxf(mx, __shfl_xor(mx, 8, 64));
      float mnew = fmaxf(m_run[r], mx);
      alpha[r] = exp2f(m_run[r] - mnew);
      m_run[r] = mnew;
      pv0[r] = exp2f(s0 - mnew);
      pv1[r] = exp2f(s1 - mnew);
    }
#pragma unroll
    for (int d = 0; d < 8; ++d) {
      f32x4_t o = oacc[d];
      o[0] *= alpha[0]; o[1] *= alpha[1]; o[2] *= alpha[2]; o[3] *= alpha[3];
      oacc[d] = o;
    }
    lacc[0] *= alpha[0]; lacc[1] *= alpha[1];
    lacc[2] *= alpha[2]; lacc[3] *= alpha[3];

    // P: C-layout regs -> per-wave LDS -> A-layout frag (same wave)
    __bf16* Pw = Pl[w];
#pragma unroll
    for (int r = 0; r < 4; ++r) {
      Pw[(quad * 4 + r) * BN + col]      = (__bf16)pv0[r];
      Pw[(quad * 4 + r) * BN + 16 + col] = (__bf16)pv1[r];
    }
    bf16x8_t pf = *(const bf16x8_t*)&Pw[col * BN + quad * 8];

    // O += P V ; l += P * ones
#pragma unroll
    for (int d = 0; d < 8; ++d) {
      bf16x8_t vf = *(const bf16x8_t*)&Vt[(d * 16 + col) * BN + quad * 8];
      oacc[d] = __builtin_amdgcn_mfma_f32_16x16x32_bf16(pf, vf, oacc[d], 0, 0, 0);
    }
    lacc = __builtin_amdgcn_mfma_f32_16x16x32_bf16(pf, vxf, lacc, 0, 0, 0);
  };

  for (int it2 = 0; it2 <= qt; ++it2) {
    // phase A: tile 2*it2 in KlA/VlA
    WAIT_VM0();                  // own DMAs (into A) done; issued a phase ago
    __syncthreads();             // -> ALL waves' DMAs into A done; B readable
    stage(2 * it2 + 1, KlB, VlB);
    compute(KlA, VlA, (2 * it2) * BN);
    // phase B: tile 2*it2+1 in KlB/VlB
    WAIT_VM0();
    __syncthreads();
    if (it2 < qt) stage(2 * it2 + 2, KlA, VlA);
    compute(KlB, VlB, (2 * it2 + 1) * BN);
  }

  // ---- epilogue: broadcast l from col-0 lanes, normalize, store
  float lr[4];
#pragma unroll
  for (int r = 0; r < 4; ++r) lr[r] = __shfl(lacc[r], lane & 48, 64);
  float inv_l[4];
#pragma unroll
  for (int r = 0; r < 4; ++r) inv_l[r] = 1.0f / lr[r];
#pragma unroll
  for (int d = 0; d < 8; ++d) {
#pragma unroll
    for (int r = 0; r < 4; ++r) {
      int mm = qb + w * 16 + quad * 4 + r;
      out_o[(size_t)((b * SEQ + mm) * NH + h) * DVDIM + d * 16 + col] = oacc[d][r] * inv_l[r];
    }
  }
  if (col < 4) {
    int r = col;
    int mm = qb + w * 16 + quad * 4 + r;
    out_lse[(size_t)(b * SEQ + mm) * NH + h] = m_run[r] + log2f(lr[r]);
  }
}

// ---------------------------------------------------------------------------
extern "C" void kernel_launch(void* const* d_in, const int* in_sizes, int n_in,
                              void* d_out, int out_size, void* d_ws, size_t ws_size,
                              hipStream_t stream) {
  const float* q_nope = (const float*)d_in[0];
  const float* q_pe   = (const float*)d_in[1];
  const float* k_nope = (const float*)d_in[2];
  const float* k_pe   = (const float*)d_in[3];
  const float* v      = (const float*)d_in[4];
  float* out_o   = (float*)d_out;
  float* out_lse = out_o + (size_t)NB * SEQ * NH * DVDIM;

  __bf16* Kbf = (__bf16*)d_ws;
  __bf16* Vtb = Kbf + KBF_ELEMS;   // total ws use ~40 MB

  prep_kernel<<<dim3(KPREP_BLOCKS + VPREP_BLOCKS), dim3(256), 0, stream>>>(
      k_nope, k_pe, v, Kbf, Vtb);
  mla_fwd_kernel<<<dim3(32, NH, NB), dim3(256), 0, stream>>>(
      q_nope, q_pe, Kbf, Vtb, out_o, out_lse);
}

// Round 5
// 321.628 us; speedup vs baseline: 1.2061x; 1.2061x over previous
//
#include <hip/hip_runtime.h>
#include <hip/hip_bf16.h>
#include <math.h>

// Problem constants (from reference setup_inputs)
#define NB 2
#define SEQ 2048
#define NH 16
#define DNOPE 128
#define DROT 64
#define DVDIM 128
#define DQK 192
#define BM 64
#define BN 64

typedef __bf16 bf16x8_t __attribute__((ext_vector_type(8)));
typedef float f32x4_t __attribute__((ext_vector_type(4)));

// log2(10000)/32 — inv_freq_i = 2^(-i*this); YaRN collapses (SCALING_FACTOR==1)
#define LOG2_BASE_OVER_HALFDIM 0.41524101186092028f
// 192^-0.5 * log2(e), folded into Q at bf16-convert time
#define KSL2 0.10412340175817158f
#define INV2PI 0.15915494309189535f

// ws layout
#define KBF_ELEMS   ((size_t)NB * NH * SEQ * DQK)          // 12,582,912
#define KPREP_BLOCKS 6144                                  // KBF_ELEMS/8/256
#define VPREP_BLOCKS 1024                                  // 32*16*2

// fast sin/cos of ang (radians, |ang|<~4096): reduce to revolutions in
// [-0.5,0.5], then v_sin/v_cos (input = revolutions). err ~2e-4 << bf16 ulp.
__device__ __forceinline__ void fast_sincos(float ang, float* sn, float* cs) {
  float rev = ang * INV2PI;
  float r = rev - rintf(rev);
  *sn = __builtin_amdgcn_sinf(r);
  *cs = __builtin_amdgcn_cosf(r);
}

// direct global->LDS DMA, 16B/lane; LDS dest is wave-uniform base + lane*16.
__device__ __forceinline__ void load_lds16(const __bf16* g, __bf16* l) {
  __builtin_amdgcn_global_load_lds(
      (const __attribute__((address_space(1))) unsigned int*)g,
      (__attribute__((address_space(3))) unsigned int*)l, 16, 0, 0);
}

// s_waitcnt vmcnt(0), expcnt/lgkm untouched (gfx9 encoding)
#define WAIT_VM0() __builtin_amdgcn_s_waitcnt(0x0F70)

// ---------------------------------------------------------------------------
// Fused prep: blocks [0,6144) build K bf16 [b][h][s][192] = concat(k_nope,
// rope(k_pe)); blocks [6144,7168) build V bf16 transposed [b][h][dv][s].
// ---------------------------------------------------------------------------
__global__ __launch_bounds__(256) void prep_kernel(
    const float* __restrict__ k_nope, const float* __restrict__ k_pe,
    const float* __restrict__ v, __bf16* __restrict__ Kbf,
    __bf16* __restrict__ Vtb) {
  __shared__ __bf16 T[64][130];
  const int bid = blockIdx.x;
  const int tid = threadIdx.x;
  if (bid < KPREP_BLOCKS) {
    int gid = bid * 256 + tid;                  // 8 elems each
    size_t o8 = (size_t)gid * 8;
    int d0 = (int)(o8 % DQK);                   // multiple of 8
    int rest = (int)(o8 / DQK);                 // (b*16+h)*2048 + s
    int s = rest & (SEQ - 1);
    int bh = rest >> 11;
    int h = bh & (NH - 1), b = bh >> 4;
    bf16x8_t o;
    if (d0 < DNOPE) {
      const float* p = k_nope + ((size_t)((b * SEQ + s) * NH + h)) * DNOPE + d0;
      float4 a = *(const float4*)p;
      float4 c = *(const float4*)(p + 4);
      o[0] = (__bf16)a.x; o[1] = (__bf16)a.y; o[2] = (__bf16)a.z; o[3] = (__bf16)a.w;
      o[4] = (__bf16)c.x; o[5] = (__bf16)c.y; o[6] = (__bf16)c.z; o[7] = (__bf16)c.w;
    } else {
      int dr0 = d0 - DNOPE;
      const float* p = k_pe + (size_t)(b * SEQ + s) * DROT;
#pragma unroll
      for (int j = 0; j < 8; ++j) {
        int dr = dr0 + j;
        int i = dr & 31;
        float invf = exp2f(-LOG2_BASE_OVER_HALFDIM * (float)i);
        float sn, cs;
        fast_sincos((float)s * invf, &sn, &cs);
        float x = p[dr];
        float oth = (dr < 32) ? -p[dr + 32] : p[dr - 32];
        o[j] = (__bf16)(x * cs + oth * sn);
      }
    }
    *(bf16x8_t*)&Kbf[o8] = o;
  } else {
    int vb = bid - KPREP_BLOCKS;
    const int s0 = (vb & 31) * 64, h = (vb >> 5) & (NH - 1), b = vb >> 9;
#pragma unroll
    for (int r = 0; r < 8; ++r) {
      int task = tid + r * 256;                 // 0..2047
      int srow = task >> 5, c4 = (task & 31) * 4;
      const float* p = v + ((size_t)((b * SEQ + s0 + srow) * NH + h)) * DVDIM + c4;
      float4 a = *(const float4*)p;
      T[srow][c4 + 0] = (__bf16)a.x; T[srow][c4 + 1] = (__bf16)a.y;
      T[srow][c4 + 2] = (__bf16)a.z; T[srow][c4 + 3] = (__bf16)a.w;
    }
    __syncthreads();
#pragma unroll
    for (int r = 0; r < 4; ++r) {
      int task = tid + r * 256;                 // 0..1023
      int dv = task >> 3, c8 = (task & 7) * 8;
      bf16x8_t o;
#pragma unroll
      for (int u = 0; u < 8; ++u) o[u] = T[c8 + u][dv];
      *(bf16x8_t*)&Vtb[((size_t)(b * NH + h) * DVDIM + dv) * SEQ + s0 + c8] = o;
    }
  }
}

// ---------------------------------------------------------------------------
// Flash attention fwd. Grid (16, NH, NB): WG bx handles q-tile pair
// {31-bx, bx} -> exactly 33 BN=64 k-iterations per WG (perfect balance),
// 512 WGs = exactly 2 per CU. Per iteration:
//   [vmcnt(0): drains K-DMA issued a full phase ago -> ~free] [barrier]
//   issue K-DMA(t+1) into the other K buffer; load V fragments for tile t
//   DIRECTLY from global into registers (contiguous bf16x8 in Vtb[dv][s],
//   identical across waves -> L1/L2 served, no LDS, no barrier);
//   compute QK(t) from LDS (XOR-swizzled, conflict-free), softmax, P LDS
//   round-trip (per-wave), PV from the V registers.
// l is accumulated by MFMA against a static ones-column tile Vx.
// ---------------------------------------------------------------------------
__global__ __launch_bounds__(256, 2) void mla_fwd_kernel(
    const float* __restrict__ q_nope, const float* __restrict__ q_pe,
    const __bf16* __restrict__ Kbf, const __bf16* __restrict__ Vtb,
    float* __restrict__ out_o, float* __restrict__ out_lse) {
  __shared__ __bf16 KlA[BN * DQK];      // 24576 B
  __shared__ __bf16 KlB[BN * DQK];      // 24576 B
  __shared__ __bf16 Pl[4][16 * BN];     //  8192 B
  __shared__ __bf16 Vx[16 * 72];        //  2304 B   -> 58.2 KB total

  const int bx = blockIdx.x, h = blockIdx.y, b = blockIdx.z;
  const int tid = threadIdx.x;
  const int w = tid >> 6, lane = tid & 63;
  const int col = lane & 15, quad = lane >> 4;
  const int swz = col & 7;
  const int e0 = quad ^ swz, e1 = (quad + 4) ^ swz;  // swizzled block slots
  const int wo = w * 512;                            // per-wave DMA base (elems)

  // ones-column tile: B[k][n]=1 iff n==0 -> lacc col 0 = row sums of P
  for (int i = tid; i < 16 * 72; i += 256)
    Vx[i] = (i < 64) ? (__bf16)1.0f : (__bf16)0.0f;

  const __bf16* Kslab = Kbf + (size_t)(b * NH + h) * SEQ * DQK;
  const __bf16* Vslab = Vtb + (size_t)(b * NH + h) * DVDIM * SEQ;

  // K staging source offsets (XOR swizzle folded into global source index)
  int kofs[6];
#pragma unroll
  for (int r = 0; r < 6; ++r) {
    int L = r * 256 + tid;                 // linear 16B block 0..1535
    int n = L / 24, jj = L - n * 24;
    int jsrc = (jj & ~7) | ((jj & 7) ^ (n & 7));
    kofs[r] = n * DQK + jsrc * 8;
  }

  __syncthreads();                         // Vx visible
  const bf16x8_t vxf0 = *(const bf16x8_t*)&Vx[col * 72 + quad * 8];
  const bf16x8_t vxf1 = *(const bf16x8_t*)&Vx[col * 72 + 32 + quad * 8];

  for (int half = 0; half < 2; ++half) {
    const int qt = half ? bx : (31 - bx);
    const int qb = qt * BM;
    const int mrow = qb + w * 16 + col;

    // ensure no DMA in flight and LDS free, then stage K tile 0 into KlA
    WAIT_VM0();
    __syncthreads();
#pragma unroll
    for (int r = 0; r < 6; ++r)
      load_lds16(Kslab + kofs[r], &KlA[r * 2048 + wo]);

    // ---- Q fragments (A-layout: A[m=lane&15][k=quad*8+j]); scale folded in.
    const float* qn = q_nope + (size_t)((b * SEQ + mrow) * NH + h) * DNOPE;
    const float* qp = q_pe   + (size_t)((b * SEQ + mrow) * NH + h) * DROT;
    bf16x8_t qfrag[6];
#pragma unroll
    for (int c = 0; c < 4; ++c) {
      const float* p = qn + c * 32 + quad * 8;
      float4 a = *(const float4*)p;
      float4 bq = *(const float4*)(p + 4);
      bf16x8_t f;
      f[0]=(__bf16)(a.x*KSL2);  f[1]=(__bf16)(a.y*KSL2);
      f[2]=(__bf16)(a.z*KSL2);  f[3]=(__bf16)(a.w*KSL2);
      f[4]=(__bf16)(bq.x*KSL2); f[5]=(__bf16)(bq.y*KSL2);
      f[6]=(__bf16)(bq.z*KSL2); f[7]=(__bf16)(bq.w*KSL2);
      qfrag[c] = f;
    }
    {
      const float* plo = qp + quad * 8;
      const float* phi = qp + 32 + quad * 8;
      float4 lo0 = *(const float4*)plo;
      float4 lo1 = *(const float4*)(plo + 4);
      float4 hi0 = *(const float4*)phi;
      float4 hi1 = *(const float4*)(phi + 4);
      float xl[8] = {lo0.x,lo0.y,lo0.z,lo0.w,lo1.x,lo1.y,lo1.z,lo1.w};
      float xh[8] = {hi0.x,hi0.y,hi0.z,hi0.w,hi1.x,hi1.y,hi1.z,hi1.w};
      bf16x8_t f4v, f5v;
#pragma unroll
      for (int j = 0; j < 8; ++j) {
        int i = quad * 8 + j;
        float invf = exp2f(-LOG2_BASE_OVER_HALFDIM * (float)i);
        float sn, cs;
        fast_sincos((float)mrow * invf, &sn, &cs);
        f4v[j] = (__bf16)((xl[j] * cs - xh[j] * sn) * KSL2);
        f5v[j] = (__bf16)((xh[j] * cs + xl[j] * sn) * KSL2);
      }
      qfrag[4] = f4v; qfrag[5] = f5v;
    }

    f32x4_t oacc[8];
#pragma unroll
    for (int i = 0; i < 8; ++i) oacc[i] = (f32x4_t){0.f, 0.f, 0.f, 0.f};
    f32x4_t lacc = (f32x4_t){0.f, 0.f, 0.f, 0.f};
    float m_run[4] = {-INFINITY, -INFINITY, -INFINITY, -INFINITY};

    auto phase = [&](const __bf16* Kc, __bf16* Kn, int it) {
      WAIT_VM0();              // drains K-DMA issued one full phase ago
      __syncthreads();         // all waves' DMAs into Kc done; Kn readable->dead
      // issue K-DMA for tile it+1 into the other buffer (clamped: last iter
      // re-stages tile qt harmlessly, keeps addresses in-bounds)
      const int nt = (it + 1 <= qt) ? it + 1 : qt;
      const __bf16* Ks = Kslab + (size_t)nt * BN * DQK;
#pragma unroll
      for (int r = 0; r < 6; ++r) load_lds16(Ks + kofs[r], &Kn[r * 2048 + wo]);

      const int kb = it * BN;
      // V fragments for THIS tile direct from global (latency hidden by QK)
      bf16x8_t vf[8][2];
#pragma unroll
      for (int d = 0; d < 8; ++d)
#pragma unroll
        for (int c = 0; c < 2; ++c)
          vf[d][c] = *(const bf16x8_t*)(Vslab + (size_t)(d * 16 + col) * SEQ +
                                        kb + c * 32 + quad * 8);

      // ---- S = Q K^T : 4 n-tiles, 6 K-chunks (pre-scaled, log2 domain)
      f32x4_t sacc[4];
#pragma unroll
      for (int t = 0; t < 4; ++t) sacc[t] = (f32x4_t){0.f, 0.f, 0.f, 0.f};
#pragma unroll
      for (int t = 0; t < 4; ++t) {
        const __bf16* kr = &Kc[(t * 16 + col) * DQK];
        sacc[t] = __builtin_amdgcn_mfma_f32_16x16x32_bf16(qfrag[0], *(const bf16x8_t*)&kr[e0 * 8], sacc[t], 0, 0, 0);
        sacc[t] = __builtin_amdgcn_mfma_f32_16x16x32_bf16(qfrag[1], *(const bf16x8_t*)&kr[e1 * 8], sacc[t], 0, 0, 0);
        sacc[t] = __builtin_amdgcn_mfma_f32_16x16x32_bf16(qfrag[2], *(const bf16x8_t*)&kr[64 + e0 * 8], sacc[t], 0, 0, 0);
        sacc[t] = __builtin_amdgcn_mfma_f32_16x16x32_bf16(qfrag[3], *(const bf16x8_t*)&kr[64 + e1 * 8], sacc[t], 0, 0, 0);
        sacc[t] = __builtin_amdgcn_mfma_f32_16x16x32_bf16(qfrag[4], *(const bf16x8_t*)&kr[128 + e0 * 8], sacc[t], 0, 0, 0);
        sacc[t] = __builtin_amdgcn_mfma_f32_16x16x32_bf16(qfrag[5], *(const bf16x8_t*)&kr[128 + e1 * 8], sacc[t], 0, 0, 0);
      }

      // ---- online softmax (log2 domain)
      const bool diag = (it == qt);
      float pv[4][4];
      float alpha[4];
#pragma unroll
      for (int r = 0; r < 4; ++r) {
        float mx = -INFINITY;
#pragma unroll
        for (int t = 0; t < 4; ++t) {
          float sv = sacc[t][r];
          if (diag) {
            int nn = kb + t * 16 + col;
            int mm = qb + w * 16 + quad * 4 + r;
            if (nn > mm) sv = -INFINITY;
          }
          pv[t][r] = sv;
          mx = fmaxf(mx, sv);
        }
        mx = fmaxf(mx, __shfl_xor(mx, 1, 64));
        mx = fmaxf(mx, __shfl_xor(mx, 2, 64));
        mx = fmaxf(mx, __shfl_xor(mx, 4, 64));
        mx = fmaxf(mx, __shfl_xor(mx, 8, 64));
        float mnew = fmaxf(m_run[r], mx);
        alpha[r] = exp2f(m_run[r] - mnew);
        m_run[r] = mnew;
#pragma unroll
        for (int t = 0; t < 4; ++t) pv[t][r] = exp2f(pv[t][r] - mnew);
      }
#pragma unroll
      for (int d = 0; d < 8; ++d) {
        f32x4_t o = oacc[d];
        o[0] *= alpha[0]; o[1] *= alpha[1]; o[2] *= alpha[2]; o[3] *= alpha[3];
        oacc[d] = o;
      }
      lacc[0] *= alpha[0]; lacc[1] *= alpha[1];
      lacc[2] *= alpha[2]; lacc[3] *= alpha[3];

      // ---- P: C-layout regs -> swizzled per-wave LDS -> A-layout frags
      __bf16* Pw = Pl[w];
#pragma unroll
      for (int t = 0; t < 4; ++t)
#pragma unroll
        for (int r = 0; r < 4; ++r) {
          int row = quad * 4 + r;
          int j = t * 2 + (col >> 3);
          Pw[(row * 8 + (j ^ (row & 7))) * 8 + (col & 7)] = (__bf16)pv[t][r];
        }
      bf16x8_t pf0 = *(const bf16x8_t*)&Pw[(col * 8 + e0) * 8];
      bf16x8_t pf1 = *(const bf16x8_t*)&Pw[(col * 8 + e1) * 8];

      // ---- O += P V (from registers) ; l += P * ones
#pragma unroll
      for (int d = 0; d < 8; ++d) {
        oacc[d] = __builtin_amdgcn_mfma_f32_16x16x32_bf16(pf0, vf[d][0], oacc[d], 0, 0, 0);
        oacc[d] = __builtin_amdgcn_mfma_f32_16x16x32_bf16(pf1, vf[d][1], oacc[d], 0, 0, 0);
      }
      lacc = __builtin_amdgcn_mfma_f32_16x16x32_bf16(pf0, vxf0, lacc, 0, 0, 0);
      lacc = __builtin_amdgcn_mfma_f32_16x16x32_bf16(pf1, vxf1, lacc, 0, 0, 0);
    };

    for (int it = 0; it <= qt; ++it) {
      if ((it & 1) == 0) phase(KlA, KlB, it);
      else               phase(KlB, KlA, it);
    }

    // ---- epilogue: broadcast l from col-0 lanes, normalize, store
    float lr[4];
#pragma unroll
    for (int r = 0; r < 4; ++r) lr[r] = __shfl(lacc[r], lane & 48, 64);
    float inv_l[4];
#pragma unroll
    for (int r = 0; r < 4; ++r) inv_l[r] = 1.0f / lr[r];
#pragma unroll
    for (int d = 0; d < 8; ++d) {
#pragma unroll
      for (int r = 0; r < 4; ++r) {
        int mm = qb + w * 16 + quad * 4 + r;
        out_o[(size_t)((b * SEQ + mm) * NH + h) * DVDIM + d * 16 + col] = oacc[d][r] * inv_l[r];
      }
    }
    if (col < 4) {
      int r = col;
      int mm = qb + w * 16 + quad * 4 + r;
      out_lse[(size_t)(b * SEQ + mm) * NH + h] = m_run[r] + log2f(lr[r]);
    }
  }
}

// ---------------------------------------------------------------------------
extern "C" void kernel_launch(void* const* d_in, const int* in_sizes, int n_in,
                              void* d_out, int out_size, void* d_ws, size_t ws_size,
                              hipStream_t stream) {
  const float* q_nope = (const float*)d_in[0];
  const float* q_pe   = (const float*)d_in[1];
  const float* k_nope = (const float*)d_in[2];
  const float* k_pe   = (const float*)d_in[3];
  const float* v      = (const float*)d_in[4];
  float* out_o   = (float*)d_out;
  float* out_lse = out_o + (size_t)NB * SEQ * NH * DVDIM;

  __bf16* Kbf = (__bf16*)d_ws;
  __bf16* Vtb = Kbf + KBF_ELEMS;   // total ws use ~40 MB

  prep_kernel<<<dim3(KPREP_BLOCKS + VPREP_BLOCKS), dim3(256), 0, stream>>>(
      k_nope, k_pe, v, Kbf, Vtb);
  mla_fwd_kernel<<<dim3(16, NH, NB), dim3(256), 0, stream>>>(
      q_nope, q_pe, Kbf, Vtb, out_o, out_lse);
}